// Round 4
// baseline (247.031 us; speedup 1.0000x reference)
//
#include <hip/hip_runtime.h>

#define C_CH 128
#define I_CH 16
#define NVOX 9216   // 16*24*24
#define BATCH 2
#define LOG2E 1.44269504088896340736f

typedef unsigned short ushort_t;
typedef unsigned int uint_t;
typedef short bf16x8 __attribute__((ext_vector_type(8)));
typedef float f32x4 __attribute__((ext_vector_type(4)));

static __device__ inline ushort_t f2bf_rne(float x) {
    uint_t u = __builtin_bit_cast(uint_t, x);
    u = (u + 0x7FFFu + ((u >> 16) & 1u)) >> 16;
    return (ushort_t)u;
}

static __device__ inline float fast_exp2(float x) {
#if __has_builtin(__builtin_amdgcn_exp2f)
    return __builtin_amdgcn_exp2f(x);
#else
    return exp2f(x);
#endif
}

// ---------------------------------------------------------------------------
// Kernel 1: QKV projection -> bf16 (q pre-scaled by log2e).
// W staged in LDS (24 KB, read as uniform-broadcast b128); x tile in LDS.
//   qb[vox][16], kb[vox][16]  (voxel-major), vT[b][i][NVOX] (i-major)
// grid: B*NVOX/64 = 288 blocks, 256 threads
// ---------------------------------------------------------------------------
__global__ __launch_bounds__(256) void qkv_kernel(
    const float* __restrict__ x,
    const float* __restrict__ Wq, const float* __restrict__ bq,
    const float* __restrict__ Wk, const float* __restrict__ bk,
    const float* __restrict__ Wv, const float* __restrict__ bv,
    ushort_t* __restrict__ qb, ushort_t* __restrict__ kb,
    ushort_t* __restrict__ vT)
{
    __shared__ float xs[C_CH][64];        // 32 KB
    __shared__ float ws[3][I_CH][C_CH];   // 24 KB

    const int blk = blockIdx.x;
    const int b   = blk / (NVOX / 64);
    const int n0  = (blk % (NVOX / 64)) * 64;
    const int t   = threadIdx.x;

    // stage W: 3 x 2048 floats = 512 float4 each, 2 per thread per matrix
    {
        float4* wsq = (float4*)&ws[0][0][0];
        float4* wsk = (float4*)&ws[1][0][0];
        float4* wsv = (float4*)&ws[2][0][0];
        wsq[t]       = ((const float4*)Wq)[t];
        wsq[t + 256] = ((const float4*)Wq)[t + 256];
        wsk[t]       = ((const float4*)Wk)[t];
        wsk[t + 256] = ((const float4*)Wk)[t + 256];
        wsv[t]       = ((const float4*)Wv)[t];
        wsv[t + 256] = ((const float4*)Wv)[t + 256];
    }

    // stage x tile: 128 ch x 64 vox, coalesced float4
    const float* xb = x + (size_t)b * C_CH * NVOX;
    #pragma unroll
    for (int rep = 0; rep < 8; ++rep) {
        int idx4 = rep * 256 + t;
        int c    = idx4 >> 4;
        int n4   = (idx4 & 15) << 2;
        *(float4*)&xs[c][n4] = *(const float4*)(xb + (size_t)c * NVOX + n0 + n4);
    }
    __syncthreads();

    const int n  = t & 63;
    const int iw = t >> 6;   // 0..3
    const int i0 = iw * 4;

    float aq[4] = {0.f,0.f,0.f,0.f};
    float ak[4] = {0.f,0.f,0.f,0.f};
    float av[4] = {0.f,0.f,0.f,0.f};

    #pragma unroll 2
    for (int c = 0; c < C_CH; c += 4) {
        float xv0 = xs[c + 0][n];
        float xv1 = xs[c + 1][n];
        float xv2 = xs[c + 2][n];
        float xv3 = xs[c + 3][n];
        #pragma unroll
        for (int j = 0; j < 4; ++j) {
            float4 w4;
            w4 = *(const float4*)&ws[0][i0 + j][c];
            aq[j] = fmaf(w4.x, xv0, fmaf(w4.y, xv1, fmaf(w4.z, xv2, fmaf(w4.w, xv3, aq[j]))));
            w4 = *(const float4*)&ws[1][i0 + j][c];
            ak[j] = fmaf(w4.x, xv0, fmaf(w4.y, xv1, fmaf(w4.z, xv2, fmaf(w4.w, xv3, ak[j]))));
            w4 = *(const float4*)&ws[2][i0 + j][c];
            av[j] = fmaf(w4.x, xv0, fmaf(w4.y, xv1, fmaf(w4.z, xv2, fmaf(w4.w, xv3, av[j]))));
        }
    }

    const size_t vox = (size_t)b * NVOX + n0 + n;
    ushort4 qv, kv;
    qv.x = f2bf_rne((aq[0] + bq[i0+0]) * LOG2E);
    qv.y = f2bf_rne((aq[1] + bq[i0+1]) * LOG2E);
    qv.z = f2bf_rne((aq[2] + bq[i0+2]) * LOG2E);
    qv.w = f2bf_rne((aq[3] + bq[i0+3]) * LOG2E);
    kv.x = f2bf_rne(ak[0] + bk[i0+0]); kv.y = f2bf_rne(ak[1] + bk[i0+1]);
    kv.z = f2bf_rne(ak[2] + bk[i0+2]); kv.w = f2bf_rne(ak[3] + bk[i0+3]);
    *(ushort4*)(qb + vox * I_CH + i0) = qv;
    *(ushort4*)(kb + vox * I_CH + i0) = kv;

    const int nl = n0 + n;
    #pragma unroll
    for (int j = 0; j < 4; ++j)
        vT[((size_t)b * I_CH + i0 + j) * NVOX + nl] = f2bf_rne(av[j] + bv[i0+j]);
}

// ---------------------------------------------------------------------------
// Kernel 2: fused MFMA flash attention + combine + output projection + resid.
// Block = 512 threads = 8 waves, 16 queries/block (grid 1152 -> ~4.5 blk/CU).
// Wave w covers keys [w*1152, (w+1)*1152) in 36 steps of 32 keys, with
// explicit register prefetch of next ka/va. Per step: 2 score MFMA
// (16x16x32, K=16 padded), 8 exp2, 4 packs, 1 PV MFMA, 1 l-MFMA (A=ones).
// Epilogue: LDS reduce of 8 partials, /l, Wo projection, residual, store.
// NOTE: prefetch reads up to ~64B past the wave's K/V range; ws has slack.
// ---------------------------------------------------------------------------
__global__ __launch_bounds__(512) void attn_kernel(
    const ushort_t* __restrict__ qb, const ushort_t* __restrict__ kb,
    const ushort_t* __restrict__ vT,
    const float* __restrict__ Wo, const float* __restrict__ bo,
    const float* __restrict__ gamma, const float* __restrict__ x,
    float* __restrict__ out)
{
    __shared__ float po[4][16][17];     // padded: stage-A/B partial O
    __shared__ float lsh[8][16];
    __shared__ float aot[16][20];       // ao transposed [i][q], pad 20
    __shared__ float wo_s[C_CH][16];    // 8 KB, dense (reads use rotated i)

    const int tid  = threadIdx.x;
    const int w    = tid >> 6;
    const int lane = tid & 63;
    const int l16  = lane & 15;
    const int quad = lane >> 4;

    // stage Wo: 2048 floats = 512 float4, 1 per thread
    ((float4*)&wo_s[0][0])[tid] = ((const float4*)Wo)[tid];

    const int qvox0 = blockIdx.x * 16;
    const int b     = qvox0 / NVOX;
    const int nloc0 = qvox0 - b * NVOX;

    // Q B-frag (B[k=i][n=q], k = quad*8+j; zero for i>=16)
    bf16x8 qf = (bf16x8)0;
    if (quad < 2)
        qf = __builtin_bit_cast(bf16x8,
             *(const int4*)(qb + (size_t)(qvox0 + l16) * I_CH + quad * 8));

    // key permutation: score-row r -> key (r>>2)*8 + (r&3)  [+4 for tile1]
    const int p0     = ((l16 >> 2) << 3) + (l16 & 3);
    const int mchunk = w * (NVOX / 8);          // 1152 keys per wave
    const ushort_t* kp = kb + ((size_t)b * NVOX + mchunk + p0) * I_CH + (quad & 1) * 8;
    const ushort_t* vp = vT + ((size_t)b * I_CH + l16) * NVOX + mchunk + quad * 8;

    f32x4 O = {0.f,0.f,0.f,0.f};
    f32x4 L = {0.f,0.f,0.f,0.f};
    const f32x4 Z = {0.f,0.f,0.f,0.f};
    int4 onesi; onesi.x = onesi.y = onesi.z = onesi.w = 0x3F803F80;  // bf16 1.0
    const bf16x8 ones = __builtin_bit_cast(bf16x8, onesi);

    int4 ka0 = *(const int4*)(kp);
    int4 ka1 = *(const int4*)(kp + 4 * I_CH);
    int4 va  = *(const int4*)(vp);

    #pragma unroll 2
    for (int it = 0; it < NVOX / 8 / 32; ++it) {
        kp += 32 * I_CH;
        vp += 32;
        int4 ka0n = *(const int4*)(kp);            // prefetch next step
        int4 ka1n = *(const int4*)(kp + 4 * I_CH);
        int4 van  = *(const int4*)(vp);

        f32x4 s0 = __builtin_amdgcn_mfma_f32_16x16x32_bf16(
            __builtin_bit_cast(bf16x8, ka0), qf, Z, 0, 0, 0);
        f32x4 s1 = __builtin_amdgcn_mfma_f32_16x16x32_bf16(
            __builtin_bit_cast(bf16x8, ka1), qf, Z, 0, 0, 0);

        float p00 = fast_exp2(s0.x), p01 = fast_exp2(s0.y);
        float p02 = fast_exp2(s0.z), p03 = fast_exp2(s0.w);
        float p10 = fast_exp2(s1.x), p11 = fast_exp2(s1.y);
        float p12 = fast_exp2(s1.z), p13 = fast_exp2(s1.w);

        uint_t d0 = __builtin_amdgcn_perm(__builtin_bit_cast(uint_t, p01),
                                          __builtin_bit_cast(uint_t, p00), 0x07060302u);
        uint_t d1 = __builtin_amdgcn_perm(__builtin_bit_cast(uint_t, p03),
                                          __builtin_bit_cast(uint_t, p02), 0x07060302u);
        uint_t d2 = __builtin_amdgcn_perm(__builtin_bit_cast(uint_t, p11),
                                          __builtin_bit_cast(uint_t, p10), 0x07060302u);
        uint_t d3 = __builtin_amdgcn_perm(__builtin_bit_cast(uint_t, p13),
                                          __builtin_bit_cast(uint_t, p12), 0x07060302u);
        int4 pbi = make_int4((int)d0, (int)d1, (int)d2, (int)d3);
        bf16x8 pb = __builtin_bit_cast(bf16x8, pbi);

        O = __builtin_amdgcn_mfma_f32_16x16x32_bf16(
            __builtin_bit_cast(bf16x8, va), pb, O, 0, 0, 0);
        L = __builtin_amdgcn_mfma_f32_16x16x32_bf16(ones, pb, L, 0, 0, 0);

        ka0 = ka0n; ka1 = ka1n; va = van;
    }

    // ---- stage A: waves 0-3 deposit O; every wave deposits l ----
    if (w < 4) {
        #pragma unroll
        for (int r = 0; r < 4; ++r) po[w][quad * 4 + r][l16] = O[r];
    }
    if (quad == 0) lsh[w][l16] = L.x;
    __syncthreads();

    // ---- stage B: waves 4-7 accumulate into slot w-4 ----
    if (w >= 4) {
        #pragma unroll
        for (int r = 0; r < 4; ++r) po[w - 4][quad * 4 + r][l16] += O[r];
    }
    __syncthreads();

    // ---- combine: 256 threads -> aot[i][q] = (sum O)/(sum l) ----
    if (tid < 256) {
        const int q = tid & 15;
        const int i = tid >> 4;
        float v = 0.f, l = 0.f;
        #pragma unroll
        for (int ww = 0; ww < 4; ++ww) v += po[ww][i][q];
        #pragma unroll
        for (int ww = 0; ww < 8; ++ww) l += lsh[ww][q];
        aot[i][q] = v / l;
    }
    __syncthreads();

    // ---- projection + residual: thread -> (c, c+64) x 4 queries ----
    const float g  = gamma[0];
    const int   q4 = (tid & 3) * 4;
    const int   c0 = tid >> 2;          // 0..127
    const int   rot = c0 & 15;          // spread wo_s bank accesses

    float4 a4[16];
    #pragma unroll
    for (int i = 0; i < 16; ++i) a4[i] = *(const float4*)&aot[i][q4];

    #pragma unroll
    for (int half = 0; half < 2; ++half) {
        const int c = c0 + half * 64;
        if (c >= C_CH) break;
        float4 acc; acc.x = acc.y = acc.z = acc.w = bo[c];
        #pragma unroll
        for (int ii = 0; ii < 16; ++ii) {
            const int i = (ii + rot) & 15;
            const float wv = wo_s[c][i];
            acc.x = fmaf(wv, a4[i].x, acc.x);
            acc.y = fmaf(wv, a4[i].y, acc.y);
            acc.z = fmaf(wv, a4[i].z, acc.z);
            acc.w = fmaf(wv, a4[i].w, acc.w);
        }
        const size_t gi = ((size_t)b * C_CH + c) * NVOX + nloc0 + q4;
        float4 xv = *(const float4*)(x + gi);
        float4 ov;
        ov.x = fmaf(g, acc.x, xv.x); ov.y = fmaf(g, acc.y, xv.y);
        ov.z = fmaf(g, acc.z, xv.z); ov.w = fmaf(g, acc.w, xv.w);
        *(float4*)(out + gi) = ov;
    }
}

// ---------------------------------------------------------------------------
extern "C" void kernel_launch(void* const* d_in, const int* in_sizes, int n_in,
                              void* d_out, int out_size, void* d_ws, size_t ws_size,
                              hipStream_t stream) {
    const float* x     = (const float*)d_in[0];
    const float* Wq    = (const float*)d_in[1];
    const float* bq    = (const float*)d_in[2];
    const float* Wk    = (const float*)d_in[3];
    const float* bk    = (const float*)d_in[4];
    const float* Wv    = (const float*)d_in[5];
    const float* bv    = (const float*)d_in[6];
    const float* Wo    = (const float*)d_in[7];
    const float* bo    = (const float*)d_in[8];
    const float* gamma = (const float*)d_in[9];
    float* out = (float*)d_out;

    ushort_t* qb = (ushort_t*)d_ws;
    ushort_t* kb = qb + (size_t)BATCH * NVOX * I_CH;
    ushort_t* vT = kb + (size_t)BATCH * NVOX * I_CH;
    // vT is followed by ws slack (>= several MB); attn prefetch may read
    // up to ~64B past vT -- safe.

    hipLaunchKernelGGL(qkv_kernel, dim3(BATCH * NVOX / 64), dim3(256), 0, stream,
                       x, Wq, bq, Wk, bk, Wv, bv, qb, kb, vT);
    hipLaunchKernelGGL(attn_kernel, dim3(BATCH * NVOX / 16), dim3(512), 0, stream,
                       qb, kb, vT, Wo, bo, gamma, x, out);
}

// Round 5
// 128.960 us; speedup vs baseline: 1.9156x; 1.9156x over previous
//
#include <hip/hip_runtime.h>

#define C_CH 128
#define I_CH 16
#define NVOX 9216   // 16*24*24
#define BATCH 2
#define LOG2E 1.44269504088896340736f

typedef unsigned short ushort_t;
typedef unsigned int uint_t;
typedef short bf16x8 __attribute__((ext_vector_type(8)));
typedef float f32x4 __attribute__((ext_vector_type(4)));

static __device__ inline ushort_t f2bf_rne(float x) {
    uint_t u = __builtin_bit_cast(uint_t, x);
    u = (u + 0x7FFFu + ((u >> 16) & 1u)) >> 16;
    return (ushort_t)u;
}

static __device__ inline float fast_exp2(float x) {
#if __has_builtin(__builtin_amdgcn_exp2f)
    return __builtin_amdgcn_exp2f(x);
#else
    return exp2f(x);
#endif
}

// ---------------------------------------------------------------------------
// Kernel 1: QKV projection -> bf16 (q pre-scaled by log2e).
// W staged in LDS (24 KB, uniform-broadcast b128 reads); x tile in LDS.
//   qb[vox][16], kb[vox][16]  (voxel-major), vT[b][i][NVOX] (i-major)
// ---------------------------------------------------------------------------
__global__ __launch_bounds__(256) void qkv_kernel(
    const float* __restrict__ x,
    const float* __restrict__ Wq, const float* __restrict__ bq,
    const float* __restrict__ Wk, const float* __restrict__ bk,
    const float* __restrict__ Wv, const float* __restrict__ bv,
    ushort_t* __restrict__ qb, ushort_t* __restrict__ kb,
    ushort_t* __restrict__ vT)
{
    __shared__ float xs[C_CH][64];        // 32 KB
    __shared__ float ws[3][I_CH][C_CH];   // 24 KB

    const int blk = blockIdx.x;
    const int b   = blk / (NVOX / 64);
    const int n0  = (blk % (NVOX / 64)) * 64;
    const int t   = threadIdx.x;

    {
        float4* wsq = (float4*)&ws[0][0][0];
        float4* wsk = (float4*)&ws[1][0][0];
        float4* wsv = (float4*)&ws[2][0][0];
        wsq[t]       = ((const float4*)Wq)[t];
        wsq[t + 256] = ((const float4*)Wq)[t + 256];
        wsk[t]       = ((const float4*)Wk)[t];
        wsk[t + 256] = ((const float4*)Wk)[t + 256];
        wsv[t]       = ((const float4*)Wv)[t];
        wsv[t + 256] = ((const float4*)Wv)[t + 256];
    }

    const float* xb = x + (size_t)b * C_CH * NVOX;
    #pragma unroll
    for (int rep = 0; rep < 8; ++rep) {
        int idx4 = rep * 256 + t;
        int c    = idx4 >> 4;
        int n4   = (idx4 & 15) << 2;
        *(float4*)&xs[c][n4] = *(const float4*)(xb + (size_t)c * NVOX + n0 + n4);
    }
    __syncthreads();

    const int n  = t & 63;
    const int iw = t >> 6;   // 0..3
    const int i0 = iw * 4;

    float aq[4] = {0.f,0.f,0.f,0.f};
    float ak[4] = {0.f,0.f,0.f,0.f};
    float av[4] = {0.f,0.f,0.f,0.f};

    #pragma unroll 2
    for (int c = 0; c < C_CH; c += 4) {
        float xv0 = xs[c + 0][n];
        float xv1 = xs[c + 1][n];
        float xv2 = xs[c + 2][n];
        float xv3 = xs[c + 3][n];
        #pragma unroll
        for (int j = 0; j < 4; ++j) {
            float4 w4;
            w4 = *(const float4*)&ws[0][i0 + j][c];
            aq[j] = fmaf(w4.x, xv0, fmaf(w4.y, xv1, fmaf(w4.z, xv2, fmaf(w4.w, xv3, aq[j]))));
            w4 = *(const float4*)&ws[1][i0 + j][c];
            ak[j] = fmaf(w4.x, xv0, fmaf(w4.y, xv1, fmaf(w4.z, xv2, fmaf(w4.w, xv3, ak[j]))));
            w4 = *(const float4*)&ws[2][i0 + j][c];
            av[j] = fmaf(w4.x, xv0, fmaf(w4.y, xv1, fmaf(w4.z, xv2, fmaf(w4.w, xv3, av[j]))));
        }
    }

    const size_t vox = (size_t)b * NVOX + n0 + n;
    ushort4 qv, kv;
    qv.x = f2bf_rne((aq[0] + bq[i0+0]) * LOG2E);
    qv.y = f2bf_rne((aq[1] + bq[i0+1]) * LOG2E);
    qv.z = f2bf_rne((aq[2] + bq[i0+2]) * LOG2E);
    qv.w = f2bf_rne((aq[3] + bq[i0+3]) * LOG2E);
    kv.x = f2bf_rne(ak[0] + bk[i0+0]); kv.y = f2bf_rne(ak[1] + bk[i0+1]);
    kv.z = f2bf_rne(ak[2] + bk[i0+2]); kv.w = f2bf_rne(ak[3] + bk[i0+3]);
    *(ushort4*)(qb + vox * I_CH + i0) = qv;
    *(ushort4*)(kb + vox * I_CH + i0) = kv;

    const int nl = n0 + n;
    #pragma unroll
    for (int j = 0; j < 4; ++j)
        vT[((size_t)b * I_CH + i0 + j) * NVOX + nl] = f2bf_rne(av[j] + bv[i0+j]);
}

// ---------------------------------------------------------------------------
// Kernel 2: fused MFMA flash attention + combine + output projection + resid.
// Block = 512 threads = 8 waves, 32 queries/block (576 blocks, 2.25 blk/CU).
// Wave w covers keys [w*1152, (w+1)*1152) in 36 steps of 32 keys, with
// register prefetch of next ka/va (hides L2 latency). Per step: 4 score
// MFMA, 16 exp2, 8 packs, 2 PV MFMA, 2 l-MFMA. Epilogue: LDS reduce,
// /l, Wo projection, residual. All LDS padded to <=2-way bank aliasing;
// NO dynamic register indexing (round-4's scratch-spill bug).
// NOTE: prefetch reads ~64B past the wave's K/V range; ws has slack.
// ---------------------------------------------------------------------------
__global__ __launch_bounds__(512) void attn_kernel(
    const ushort_t* __restrict__ qb, const ushort_t* __restrict__ kb,
    const ushort_t* __restrict__ vT,
    const float* __restrict__ Wo, const float* __restrict__ bo,
    const float* __restrict__ gamma, const float* __restrict__ x,
    float* __restrict__ out)
{
    __shared__ float po[4][32][18];     // partial O; stride 18 -> <=2-way
    __shared__ float lsh[8][33];        // per-wave l (32 q), stride 33
    __shared__ float aot[16][40];       // ao[i][q], stride 40 (16B-aligned rows)
    __shared__ float wo_s[C_CH][17];    // Wo, stride 17 -> conflict-free

    const int tid  = threadIdx.x;
    const int w    = tid >> 6;
    const int lane = tid & 63;
    const int l16  = lane & 15;
    const int quad = lane >> 4;

    // stage Wo: thread -> (c = tid>>2, i0 = (tid&3)*4), coalesced float4 read
    {
        const int c  = tid >> 2;
        const int i4 = (tid & 3) * 4;
        float4 wv = *(const float4*)(Wo + c * I_CH + i4);
        wo_s[c][i4 + 0] = wv.x; wo_s[c][i4 + 1] = wv.y;
        wo_s[c][i4 + 2] = wv.z; wo_s[c][i4 + 3] = wv.w;
    }

    const int qvox0 = blockIdx.x * 32;
    const int b     = qvox0 / NVOX;
    const int nloc0 = qvox0 - b * NVOX;

    // Q B-frags (B[k=i][n=q], k = quad*8+j; zero for i>=16)
    bf16x8 qf0 = (bf16x8)0, qf1 = (bf16x8)0;
    if (quad < 2) {
        qf0 = __builtin_bit_cast(bf16x8,
              *(const int4*)(qb + (size_t)(qvox0 + l16) * I_CH + quad * 8));
        qf1 = __builtin_bit_cast(bf16x8,
              *(const int4*)(qb + (size_t)(qvox0 + 16 + l16) * I_CH + quad * 8));
    }

    // key permutation: score-row r -> key (r>>2)*8 + (r&3)  [+4 for tile1]
    const int p0     = ((l16 >> 2) << 3) + (l16 & 3);
    const int mchunk = w * (NVOX / 8);          // 1152 keys per wave
    const ushort_t* kp = kb + ((size_t)b * NVOX + mchunk + p0) * I_CH + (quad & 1) * 8;
    const ushort_t* vp = vT + ((size_t)b * I_CH + l16) * NVOX + mchunk + quad * 8;

    f32x4 O0 = {0.f,0.f,0.f,0.f}, O1 = {0.f,0.f,0.f,0.f};
    f32x4 L0 = {0.f,0.f,0.f,0.f}, L1 = {0.f,0.f,0.f,0.f};
    const f32x4 Z = {0.f,0.f,0.f,0.f};
    int4 onesi; onesi.x = onesi.y = onesi.z = onesi.w = 0x3F803F80;  // bf16 1.0
    const bf16x8 ones = __builtin_bit_cast(bf16x8, onesi);

    int4 ka0 = *(const int4*)(kp);
    int4 ka1 = *(const int4*)(kp + 4 * I_CH);
    int4 va  = *(const int4*)(vp);

    #pragma unroll 2
    for (int it = 0; it < NVOX / 8 / 32; ++it) {
        kp += 32 * I_CH;
        vp += 32;
        int4 ka0n = *(const int4*)(kp);            // prefetch next step
        int4 ka1n = *(const int4*)(kp + 4 * I_CH);
        int4 van  = *(const int4*)(vp);

        f32x4 s00 = __builtin_amdgcn_mfma_f32_16x16x32_bf16(
            __builtin_bit_cast(bf16x8, ka0), qf0, Z, 0, 0, 0);
        f32x4 s01 = __builtin_amdgcn_mfma_f32_16x16x32_bf16(
            __builtin_bit_cast(bf16x8, ka1), qf0, Z, 0, 0, 0);
        f32x4 s10 = __builtin_amdgcn_mfma_f32_16x16x32_bf16(
            __builtin_bit_cast(bf16x8, ka0), qf1, Z, 0, 0, 0);
        f32x4 s11 = __builtin_amdgcn_mfma_f32_16x16x32_bf16(
            __builtin_bit_cast(bf16x8, ka1), qf1, Z, 0, 0, 0);

        // qtile 0
        {
            float p00 = fast_exp2(s00.x), p01 = fast_exp2(s00.y);
            float p02 = fast_exp2(s00.z), p03 = fast_exp2(s00.w);
            float p10 = fast_exp2(s01.x), p11 = fast_exp2(s01.y);
            float p12 = fast_exp2(s01.z), p13 = fast_exp2(s01.w);
            uint_t d0 = __builtin_amdgcn_perm(__builtin_bit_cast(uint_t, p01),
                                              __builtin_bit_cast(uint_t, p00), 0x07060302u);
            uint_t d1 = __builtin_amdgcn_perm(__builtin_bit_cast(uint_t, p03),
                                              __builtin_bit_cast(uint_t, p02), 0x07060302u);
            uint_t d2 = __builtin_amdgcn_perm(__builtin_bit_cast(uint_t, p11),
                                              __builtin_bit_cast(uint_t, p10), 0x07060302u);
            uint_t d3 = __builtin_amdgcn_perm(__builtin_bit_cast(uint_t, p13),
                                              __builtin_bit_cast(uint_t, p12), 0x07060302u);
            int4 pbi = make_int4((int)d0, (int)d1, (int)d2, (int)d3);
            bf16x8 pb = __builtin_bit_cast(bf16x8, pbi);
            O0 = __builtin_amdgcn_mfma_f32_16x16x32_bf16(
                __builtin_bit_cast(bf16x8, va), pb, O0, 0, 0, 0);
            L0 = __builtin_amdgcn_mfma_f32_16x16x32_bf16(ones, pb, L0, 0, 0, 0);
        }
        // qtile 1
        {
            float p00 = fast_exp2(s10.x), p01 = fast_exp2(s10.y);
            float p02 = fast_exp2(s10.z), p03 = fast_exp2(s10.w);
            float p10 = fast_exp2(s11.x), p11 = fast_exp2(s11.y);
            float p12 = fast_exp2(s11.z), p13 = fast_exp2(s11.w);
            uint_t d0 = __builtin_amdgcn_perm(__builtin_bit_cast(uint_t, p01),
                                              __builtin_bit_cast(uint_t, p00), 0x07060302u);
            uint_t d1 = __builtin_amdgcn_perm(__builtin_bit_cast(uint_t, p03),
                                              __builtin_bit_cast(uint_t, p02), 0x07060302u);
            uint_t d2 = __builtin_amdgcn_perm(__builtin_bit_cast(uint_t, p11),
                                              __builtin_bit_cast(uint_t, p10), 0x07060302u);
            uint_t d3 = __builtin_amdgcn_perm(__builtin_bit_cast(uint_t, p13),
                                              __builtin_bit_cast(uint_t, p12), 0x07060302u);
            int4 pbi = make_int4((int)d0, (int)d1, (int)d2, (int)d3);
            bf16x8 pb = __builtin_bit_cast(bf16x8, pbi);
            O1 = __builtin_amdgcn_mfma_f32_16x16x32_bf16(
                __builtin_bit_cast(bf16x8, va), pb, O1, 0, 0, 0);
            L1 = __builtin_amdgcn_mfma_f32_16x16x32_bf16(ones, pb, L1, 0, 0, 0);
        }

        ka0 = ka0n; ka1 = ka1n; va = van;
    }

    // ---- stage A: waves 0-3 deposit O; every wave deposits l ----
    if (w < 4) {
        #pragma unroll
        for (int r = 0; r < 4; ++r) {
            po[w][quad * 4 + r][l16]      = O0[r];   // qtile0: rows 0..15
            po[w][16 + quad * 4 + r][l16] = O1[r];   // qtile1: rows 16..31
        }
    }
    if (quad == 0) { lsh[w][l16] = L0.x; lsh[w][16 + l16] = L1.x; }
    __syncthreads();

    // ---- stage B: waves 4-7 accumulate into slot w-4 ----
    if (w >= 4) {
        #pragma unroll
        for (int r = 0; r < 4; ++r) {
            po[w - 4][quad * 4 + r][l16]      += O0[r];
            po[w - 4][16 + quad * 4 + r][l16] += O1[r];
        }
    }
    __syncthreads();

    // ---- combine: 512 threads -> aot[i][q] = (sum O)/(sum l) ----
    {
        const int q32 = tid & 31;
        const int i   = tid >> 5;           // 0..15
        const int row = (q32 >> 4) * 16 + i;
        const int col = q32 & 15;
        float v = 0.f, l = 0.f;
        #pragma unroll
        for (int ww = 0; ww < 4; ++ww) v += po[ww][row][col];
        #pragma unroll
        for (int ww = 0; ww < 8; ++ww) l += lsh[ww][q32];
        aot[i][q32] = v / l;
    }
    __syncthreads();

    // ---- projection + residual: thread -> (c = tid>>2, 8 queries) ----
    const float g  = gamma[0];
    const int   c  = tid >> 2;          // 0..127
    const int   qh = (tid & 3) * 8;     // 0,8,16,24

    float acc[8];
    {
        const float b0 = bo[c];
        #pragma unroll
        for (int q = 0; q < 8; ++q) acc[q] = b0;
    }
    #pragma unroll
    for (int i = 0; i < 16; ++i) {
        const float wv = wo_s[c][i];
        float4 a0 = *(const float4*)&aot[i][qh];
        float4 a1 = *(const float4*)&aot[i][qh + 4];
        acc[0] = fmaf(wv, a0.x, acc[0]); acc[1] = fmaf(wv, a0.y, acc[1]);
        acc[2] = fmaf(wv, a0.z, acc[2]); acc[3] = fmaf(wv, a0.w, acc[3]);
        acc[4] = fmaf(wv, a1.x, acc[4]); acc[5] = fmaf(wv, a1.y, acc[5]);
        acc[6] = fmaf(wv, a1.z, acc[6]); acc[7] = fmaf(wv, a1.w, acc[7]);
    }

    const size_t gi = ((size_t)b * C_CH + c) * NVOX + nloc0 + qh;
    float4 x0 = *(const float4*)(x + gi);
    float4 x1 = *(const float4*)(x + gi + 4);
    float4 o0, o1;
    o0.x = fmaf(g, acc[0], x0.x); o0.y = fmaf(g, acc[1], x0.y);
    o0.z = fmaf(g, acc[2], x0.z); o0.w = fmaf(g, acc[3], x0.w);
    o1.x = fmaf(g, acc[4], x1.x); o1.y = fmaf(g, acc[5], x1.y);
    o1.z = fmaf(g, acc[6], x1.z); o1.w = fmaf(g, acc[7], x1.w);
    *(float4*)(out + gi)     = o0;
    *(float4*)(out + gi + 4) = o1;
}

// ---------------------------------------------------------------------------
extern "C" void kernel_launch(void* const* d_in, const int* in_sizes, int n_in,
                              void* d_out, int out_size, void* d_ws, size_t ws_size,
                              hipStream_t stream) {
    const float* x     = (const float*)d_in[0];
    const float* Wq    = (const float*)d_in[1];
    const float* bq    = (const float*)d_in[2];
    const float* bk    = (const float*)d_in[4];
    const float* Wk    = (const float*)d_in[3];
    const float* bv    = (const float*)d_in[6];
    const float* Wv    = (const float*)d_in[5];
    const float* Wo    = (const float*)d_in[7];
    const float* bo    = (const float*)d_in[8];
    const float* gamma = (const float*)d_in[9];
    float* out = (float*)d_out;

    ushort_t* qb = (ushort_t*)d_ws;
    ushort_t* kb = qb + (size_t)BATCH * NVOX * I_CH;
    ushort_t* vT = kb + (size_t)BATCH * NVOX * I_CH;
    // vT is followed by ws slack; attn prefetch may read ~64B past vT (safe).

    hipLaunchKernelGGL(qkv_kernel, dim3(BATCH * NVOX / 64), dim3(256), 0, stream,
                       x, Wq, bq, Wk, bk, Wv, bv, qb, kb, vT);
    hipLaunchKernelGGL(attn_kernel, dim3(BATCH * NVOX / 32), dim3(512), 0, stream,
                       qb, kb, vT, Wo, bo, gamma, x, out);
}